// Round 1
// baseline (457.901 us; speedup 1.0000x reference)
//
#include <hip/hip_runtime.h>
#include <cstdio>

// ---------------- problem constants ----------------
constexpr int T  = 2 * 2048;   // B*S tokens
constexpr int D  = 1024;       // n_embed
constexpr int M  = 1408;       // n_moe_mlp
constexpr int E  = 8;          // experts
constexpr int TOPK = 2;

constexpr int TM = 128;        // token-rows per tile
constexpr int TN = 64;         // output cols per tile
constexpr int BK = 32;         // K-step (MFMA K=32)
constexpr int RCAP = T * TOPK + E * TM;  // padded row capacity (9216+ slack)

static_assert(D % BK == 0 && M % BK == 0, "");
static_assert(M % TN == 0 && D % TN == 0, "");

typedef _Float16 half8 __attribute__((ext_vector_type(8)));
typedef float    floatx4 __attribute__((ext_vector_type(4)));

// ---------------- ws layout (bytes) ----------------
constexpr size_t OFF_COUNTS = 0;                       // E ints
constexpr size_t OFF_BASE   = 64;                      // E ints
constexpr size_t OFF_PC     = 128;                     // E ints (padded counts)
constexpr size_t OFF_TOTAL  = 192;                     // 1 int
constexpr size_t OFF_TLIST  = 256;                     // E*T ints
constexpr size_t OFF_PLIST  = OFF_TLIST + (size_t)E * T * 4;
constexpr size_t OFF_XG     = OFF_PLIST + (size_t)E * T * 4;          // RCAP x D fp16
constexpr size_t OFF_HID    = OFF_XG  + (size_t)RCAP * D * 2;         // RCAP x M fp16
constexpr size_t OFF_WGT    = OFF_HID + (size_t)RCAP * M * 2;         // E x M x D fp16
constexpr size_t OFF_WUT    = OFF_WGT + (size_t)E * M * D * 2;
constexpr size_t OFF_WDT    = OFF_WUT + (size_t)E * M * D * 2;        // E x D x M fp16
constexpr size_t WS_NEED    = OFF_WDT + (size_t)E * D * M * 2;

// ---------------- router: scores, top-2, softmax, lists ----------------
__global__ __launch_bounds__(256) void k_router(
    const float* __restrict__ x, const float* __restrict__ wgate,
    int* __restrict__ counts, int* __restrict__ tlist, float* __restrict__ plist) {
  int wave = threadIdx.x >> 6, lane = threadIdx.x & 63;
  int t = blockIdx.x * 4 + wave;
  const float* xr = x + (size_t)t * D;
  float acc[E] = {0.f,0.f,0.f,0.f,0.f,0.f,0.f,0.f};
  #pragma unroll
  for (int i = 0; i < D / 64; ++i) {
    int d = i * 64 + lane;
    float xv = xr[d];
    const float4* wr = (const float4*)(wgate + (size_t)d * E);
    float4 w0 = wr[0], w1 = wr[1];
    acc[0] += xv * w0.x; acc[1] += xv * w0.y; acc[2] += xv * w0.z; acc[3] += xv * w0.w;
    acc[4] += xv * w1.x; acc[5] += xv * w1.y; acc[6] += xv * w1.z; acc[7] += xv * w1.w;
  }
  #pragma unroll
  for (int e = 0; e < E; ++e) {
    #pragma unroll
    for (int off = 32; off; off >>= 1) acc[e] += __shfl_xor(acc[e], off, 64);
  }
  if (lane == 0) {
    int i0 = 0; float s0 = acc[0];
    #pragma unroll
    for (int e = 1; e < E; ++e) if (acc[e] > s0) { s0 = acc[e]; i0 = e; }
    int i1 = -1; float s1 = -1e30f;
    #pragma unroll
    for (int e = 0; e < E; ++e) if (e != i0 && acc[e] > s1) { s1 = acc[e]; i1 = e; }
    float p0 = 1.f / (1.f + expf(s1 - s0));   // stable 2-way softmax (s0 >= s1)
    float p1 = 1.f - p0;
    int pos = atomicAdd(&counts[i0], 1);
    tlist[i0 * T + pos] = t; plist[i0 * T + pos] = p0;
    pos = atomicAdd(&counts[i1], 1);
    tlist[i1 * T + pos] = t; plist[i1 * T + pos] = p1;
  }
}

// ---------------- scan: padded per-expert bases ----------------
__global__ void k_scan(const int* __restrict__ counts, int* __restrict__ base,
                       int* __restrict__ pc, int* __restrict__ total) {
  if (threadIdx.x == 0 && blockIdx.x == 0) {
    int b = 0;
    for (int e = 0; e < E; ++e) {
      base[e] = b;
      int p = (counts[e] + TM - 1) / TM * TM;
      pc[e] = p; b += p;
    }
    *total = b;
  }
}

// ---------------- gather tokens -> fp16, zero pad rows ----------------
__global__ __launch_bounds__(256) void k_gather(
    const float* __restrict__ x, const int* __restrict__ counts,
    const int* __restrict__ base, const int* __restrict__ pc,
    const int* __restrict__ total, const int* __restrict__ tlist,
    _Float16* __restrict__ Xg) {
  int r = blockIdx.x;
  if (r >= *total) return;
  int e = 0;
  while (e < E - 1 && r >= base[e] + pc[e]) ++e;
  int local = r - base[e];
  int d = threadIdx.x * 4;
  union { _Float16 h[4]; ushort4 u; } o;
  if (local < counts[e]) {
    int t = tlist[e * T + local];
    float4 v = *(const float4*)(x + (size_t)t * D + d);
    o.h[0] = (_Float16)v.x; o.h[1] = (_Float16)v.y;
    o.h[2] = (_Float16)v.z; o.h[3] = (_Float16)v.w;
  } else {
    o.h[0] = (_Float16)0.f; o.h[1] = (_Float16)0.f;
    o.h[2] = (_Float16)0.f; o.h[3] = (_Float16)0.f;
  }
  *(ushort4*)(Xg + (size_t)r * D + d) = o.u;
}

// ---------------- transpose-convert: [E][R][C] f32 -> [E][C][R] f16 ----------------
__global__ __launch_bounds__(256) void k_transpose(
    const float* __restrict__ src, _Float16* __restrict__ dst, int R, int C) {
  __shared__ float tile[32][33];
  int e = blockIdx.z, rt = blockIdx.y, ct = blockIdx.x;
  int tr  = threadIdx.x >> 3;          // 0..31
  int tc4 = (threadIdx.x & 7) * 4;     // 0,4,...,28
  const float* s = src + ((size_t)e * R + rt * 32 + tr) * C + ct * 32 + tc4;
  float4 v = *(const float4*)s;
  tile[tr][tc4 + 0] = v.x; tile[tr][tc4 + 1] = v.y;
  tile[tr][tc4 + 2] = v.z; tile[tr][tc4 + 3] = v.w;
  __syncthreads();
  union { _Float16 h[4]; ushort4 u; } o;
  #pragma unroll
  for (int i = 0; i < 4; ++i) o.h[i] = (_Float16)tile[tc4 + i][tr];
  *(ushort4*)(dst + ((size_t)e * C + ct * 32 + tr) * R + rt * 32 + tc4) = o.u;
}

// ---------------- fused gate+up grouped GEMM + SiLU ----------------
__global__ __launch_bounds__(256) void k_upgate(
    const _Float16* __restrict__ Xg, const _Float16* __restrict__ wgT,
    const _Float16* __restrict__ wuT, _Float16* __restrict__ Hid,
    const int* __restrict__ base, const int* __restrict__ pc) {
  int e = blockIdx.z, mt = blockIdx.y, nt = blockIdx.x;
  int pce = pc[e];
  if (mt * TM >= pce) return;
  int row0 = base[e] + mt * TM;
  int n0 = nt * TN;
  __shared__ _Float16 As[TM][40] __attribute__((aligned(16)));
  __shared__ _Float16 Bg[TN][40] __attribute__((aligned(16)));
  __shared__ _Float16 Bu[TN][40] __attribute__((aligned(16)));
  int tid = threadIdx.x;
  int wv = tid >> 6, lane = tid & 63, lrow = lane & 15, quad = lane >> 4;
  floatx4 accg[2][4] = {};
  floatx4 accu[2][4] = {};
  const _Float16* wg_e = wgT + (size_t)e * M * D;
  const _Float16* wu_e = wuT + (size_t)e * M * D;
  for (int k0 = 0; k0 < D; k0 += BK) {
    #pragma unroll
    for (int i = 0; i < 2; ++i) {
      int idx = tid + i * 256, r = idx >> 2, seg = idx & 3;
      *(uint4*)&As[r][seg * 8] =
          *(const uint4*)(Xg + (size_t)(row0 + r) * D + k0 + seg * 8);
    }
    {
      int r = tid >> 2, seg = tid & 3;
      *(uint4*)&Bg[r][seg * 8] =
          *(const uint4*)(wg_e + (size_t)(n0 + r) * D + k0 + seg * 8);
      *(uint4*)&Bu[r][seg * 8] =
          *(const uint4*)(wu_e + (size_t)(n0 + r) * D + k0 + seg * 8);
    }
    __syncthreads();
    half8 af[2], bg[4], bu[4];
    #pragma unroll
    for (int s = 0; s < 2; ++s)
      af[s] = *(const half8*)&As[wv * 32 + s * 16 + lrow][quad * 8];
    #pragma unroll
    for (int c = 0; c < 4; ++c) {
      bg[c] = *(const half8*)&Bg[c * 16 + lrow][quad * 8];
      bu[c] = *(const half8*)&Bu[c * 16 + lrow][quad * 8];
    }
    #pragma unroll
    for (int s = 0; s < 2; ++s) {
      #pragma unroll
      for (int c = 0; c < 4; ++c) {
        accg[s][c] = __builtin_amdgcn_mfma_f32_16x16x32_f16(af[s], bg[c], accg[s][c], 0, 0, 0);
        accu[s][c] = __builtin_amdgcn_mfma_f32_16x16x32_f16(af[s], bu[c], accu[s][c], 0, 0, 0);
      }
    }
    __syncthreads();
  }
  // epilogue: h = silu(g) * u -> fp16
  #pragma unroll
  for (int s = 0; s < 2; ++s) {
    #pragma unroll
    for (int reg = 0; reg < 4; ++reg) {
      int row = row0 + wv * 32 + s * 16 + quad * 4 + reg;
      _Float16* hrow = Hid + (size_t)row * M + n0;
      #pragma unroll
      for (int c = 0; c < 4; ++c) {
        float g = accg[s][c][reg], u = accu[s][c][reg];
        float h = g / (1.f + expf(-g)) * u;
        hrow[c * 16 + lrow] = (_Float16)h;
      }
    }
  }
}

// ---------------- down grouped GEMM + weighted scatter ----------------
__global__ __launch_bounds__(256) void k_down(
    const _Float16* __restrict__ Hid, const _Float16* __restrict__ wdT,
    float* __restrict__ out, const int* __restrict__ counts,
    const int* __restrict__ base, const int* __restrict__ pc,
    const int* __restrict__ tlist, const float* __restrict__ plist) {
  int e = blockIdx.z, mt = blockIdx.y, nt = blockIdx.x;
  int pce = pc[e];
  if (mt * TM >= pce) return;
  int row0 = base[e] + mt * TM;
  int d0 = nt * TN;
  __shared__ _Float16 As[TM][40] __attribute__((aligned(16)));
  __shared__ _Float16 Bs[TN][40] __attribute__((aligned(16)));
  int tid = threadIdx.x;
  int wv = tid >> 6, lane = tid & 63, lrow = lane & 15, quad = lane >> 4;
  floatx4 acc[2][4] = {};
  const _Float16* wd_e = wdT + (size_t)e * D * M;
  for (int k0 = 0; k0 < M; k0 += BK) {   // 44 iterations
    #pragma unroll
    for (int i = 0; i < 2; ++i) {
      int idx = tid + i * 256, r = idx >> 2, seg = idx & 3;
      *(uint4*)&As[r][seg * 8] =
          *(const uint4*)(Hid + (size_t)(row0 + r) * M + k0 + seg * 8);
    }
    {
      int r = tid >> 2, seg = tid & 3;
      *(uint4*)&Bs[r][seg * 8] =
          *(const uint4*)(wd_e + (size_t)(d0 + r) * M + k0 + seg * 8);
    }
    __syncthreads();
    half8 af[2], bf[4];
    #pragma unroll
    for (int s = 0; s < 2; ++s)
      af[s] = *(const half8*)&As[wv * 32 + s * 16 + lrow][quad * 8];
    #pragma unroll
    for (int c = 0; c < 4; ++c)
      bf[c] = *(const half8*)&Bs[c * 16 + lrow][quad * 8];
    #pragma unroll
    for (int s = 0; s < 2; ++s) {
      #pragma unroll
      for (int c = 0; c < 4; ++c)
        acc[s][c] = __builtin_amdgcn_mfma_f32_16x16x32_f16(af[s], bf[c], acc[s][c], 0, 0, 0);
    }
    __syncthreads();
  }
  int cnt = counts[e];
  const int* tl = tlist + (size_t)e * T;
  const float* pl = plist + (size_t)e * T;
  #pragma unroll
  for (int s = 0; s < 2; ++s) {
    #pragma unroll
    for (int reg = 0; reg < 4; ++reg) {
      int rl = mt * TM + wv * 32 + s * 16 + quad * 4 + reg;  // local row in expert
      if (rl < cnt) {
        int t = tl[rl]; float p = pl[rl];
        float* orow = out + (size_t)t * D + d0;
        #pragma unroll
        for (int c = 0; c < 4; ++c)
          atomicAdd(&orow[c * 16 + lrow], p * acc[s][c][reg]);
      }
    }
  }
}

// ---------------- launch ----------------
extern "C" void kernel_launch(void* const* d_in, const int* in_sizes, int n_in,
                              void* d_out, int out_size, void* d_ws, size_t ws_size,
                              hipStream_t stream) {
  const float* x     = (const float*)d_in[0];
  const float* wgate = (const float*)d_in[1];
  const float* w_g   = (const float*)d_in[2];
  const float* w_u   = (const float*)d_in[3];
  const float* w_d   = (const float*)d_in[4];
  float* out = (float*)d_out;
  char* ws = (char*)d_ws;

  if (ws_size < WS_NEED) {
    fprintf(stderr, "kernel_launch: ws_size=%zu < needed %zu\n", ws_size, WS_NEED);
    return;
  }

  int* counts = (int*)(ws + OFF_COUNTS);
  int* base   = (int*)(ws + OFF_BASE);
  int* pcn    = (int*)(ws + OFF_PC);
  int* total  = (int*)(ws + OFF_TOTAL);
  int* tlist  = (int*)(ws + OFF_TLIST);
  float* plist = (float*)(ws + OFF_PLIST);
  _Float16* Xg  = (_Float16*)(ws + OFF_XG);
  _Float16* Hid = (_Float16*)(ws + OFF_HID);
  _Float16* wgT = (_Float16*)(ws + OFF_WGT);
  _Float16* wuT = (_Float16*)(ws + OFF_WUT);
  _Float16* wdT = (_Float16*)(ws + OFF_WDT);

  hipMemsetAsync(ws, 0, 256, stream);                       // counts/base/pc/total
  hipMemsetAsync(d_out, 0, (size_t)T * D * sizeof(float), stream);

  k_router<<<T / 4, 256, 0, stream>>>(x, wgate, counts, tlist, plist);
  k_scan<<<1, 64, 0, stream>>>(counts, base, pcn, total);
  k_gather<<<RCAP, 256, 0, stream>>>(x, counts, base, pcn, total, tlist, Xg);

  k_transpose<<<dim3(M / 32, D / 32, E), 256, 0, stream>>>(w_g, wgT, D, M);
  k_transpose<<<dim3(M / 32, D / 32, E), 256, 0, stream>>>(w_u, wuT, D, M);
  k_transpose<<<dim3(D / 32, M / 32, E), 256, 0, stream>>>(w_d, wdT, M, D);

  k_upgate<<<dim3(M / TN, T / TM, E), 256, 0, stream>>>(Xg, wgT, wuT, Hid, base, pcn);
  k_down<<<dim3(D / TN, T / TM, E), 256, 0, stream>>>(Hid, wdT, out, counts, base, pcn,
                                                      tlist, plist);
}

// Round 2
// 446.446 us; speedup vs baseline: 1.0257x; 1.0257x over previous
//
#include <hip/hip_runtime.h>
#include <cstdio>

// ---------------- problem constants ----------------
constexpr int T  = 4096;       // B*S tokens
constexpr int D  = 1024;       // n_embed
constexpr int M  = 1408;       // n_moe_mlp
constexpr int E  = 8;          // experts

constexpr int TM = 128;        // token-rows per tile
constexpr int TN = 128;        // output cols per tile
constexpr int BK = 32;         // K-step
constexpr int RCAP = T * 2 + E * TM;  // 9216 padded row capacity

typedef _Float16 half8 __attribute__((ext_vector_type(8)));
typedef _Float16 half4 __attribute__((ext_vector_type(4)));
typedef float    floatx4 __attribute__((ext_vector_type(4)));

// ---------------- ws layout (bytes) ----------------
constexpr size_t OFF_COUNTS = 0;                        // E ints
constexpr size_t OFF_BASE   = 64;                       // E ints
constexpr size_t OFF_PC     = 128;                      // E ints
constexpr size_t OFF_TOTAL  = 192;                      // 1 int
constexpr size_t OFF_T2E    = 256;                      // 2T ints
constexpr size_t OFF_T2POS  = OFF_T2E   + (size_t)2 * T * 4;
constexpr size_t OFF_T2P    = OFF_T2POS + (size_t)2 * T * 4;
constexpr size_t OFF_TLIST  = OFF_T2P   + (size_t)2 * T * 4;   // E*T ints
constexpr size_t OFF_XG     = OFF_TLIST + (size_t)E * T * 4;   // RCAP x D fp16 (reused as Yp)
constexpr size_t OFF_HID    = OFF_XG  + (size_t)RCAP * D * 2;  // RCAP x M fp16
constexpr size_t OFF_WGT    = OFF_HID + (size_t)RCAP * M * 2;  // E x M x D fp16
constexpr size_t OFF_WUT    = OFF_WGT + (size_t)E * M * D * 2;
constexpr size_t OFF_WDT    = OFF_WUT + (size_t)E * M * D * 2; // E x D x M fp16
constexpr size_t WS_NEED    = OFF_WDT + (size_t)E * D * M * 2;

// async global->LDS, 16B per lane. LDS dest = wave-uniform base + lane*16.
__device__ __forceinline__ void gl_lds16(const void* g, void* l) {
  __builtin_amdgcn_global_load_lds(
      (const __attribute__((address_space(1))) unsigned int*)g,
      (__attribute__((address_space(3))) unsigned int*)l, 16, 0, 0);
}

// ---------------- router ----------------
__global__ __launch_bounds__(256) void k_router(
    const float* __restrict__ x, const float* __restrict__ wgate,
    int* __restrict__ counts, int* __restrict__ tlist,
    int* __restrict__ t2e, int* __restrict__ t2pos, float* __restrict__ t2p) {
  int wave = threadIdx.x >> 6, lane = threadIdx.x & 63;
  int t = blockIdx.x * 4 + wave;
  const float* xr = x + (size_t)t * D;
  float acc[E] = {0.f,0.f,0.f,0.f,0.f,0.f,0.f,0.f};
  #pragma unroll
  for (int i = 0; i < D / 64; ++i) {
    int d = i * 64 + lane;
    float xv = xr[d];
    const float4* wr = (const float4*)(wgate + (size_t)d * E);
    float4 w0 = wr[0], w1 = wr[1];
    acc[0] += xv * w0.x; acc[1] += xv * w0.y; acc[2] += xv * w0.z; acc[3] += xv * w0.w;
    acc[4] += xv * w1.x; acc[5] += xv * w1.y; acc[6] += xv * w1.z; acc[7] += xv * w1.w;
  }
  #pragma unroll
  for (int e = 0; e < E; ++e) {
    #pragma unroll
    for (int off = 32; off; off >>= 1) acc[e] += __shfl_xor(acc[e], off, 64);
  }
  if (lane == 0) {
    int i0 = 0; float s0 = acc[0];
    #pragma unroll
    for (int e = 1; e < E; ++e) if (acc[e] > s0) { s0 = acc[e]; i0 = e; }
    int i1 = -1; float s1 = -1e30f;
    #pragma unroll
    for (int e = 0; e < E; ++e) if (e != i0 && acc[e] > s1) { s1 = acc[e]; i1 = e; }
    float p0 = 1.f / (1.f + expf(s1 - s0));   // stable 2-way softmax
    float p1 = 1.f - p0;
    int pos = atomicAdd(&counts[i0], 1);
    tlist[i0 * T + pos] = t;
    t2e[2 * t] = i0; t2pos[2 * t] = pos; t2p[2 * t] = p0;
    pos = atomicAdd(&counts[i1], 1);
    tlist[i1 * T + pos] = t;
    t2e[2 * t + 1] = i1; t2pos[2 * t + 1] = pos; t2p[2 * t + 1] = p1;
  }
}

// ---------------- scan ----------------
__global__ void k_scan(const int* __restrict__ counts, int* __restrict__ base,
                       int* __restrict__ pc, int* __restrict__ total) {
  if (threadIdx.x == 0 && blockIdx.x == 0) {
    int b = 0;
    for (int e = 0; e < E; ++e) {
      base[e] = b;
      int p = (counts[e] + TM - 1) / TM * TM;
      pc[e] = p; b += p;
    }
    *total = b;
  }
}

// ---------------- gather tokens -> fp16, zero pad rows ----------------
__global__ __launch_bounds__(256) void k_gather(
    const float* __restrict__ x, const int* __restrict__ counts,
    const int* __restrict__ base, const int* __restrict__ pc,
    const int* __restrict__ total, const int* __restrict__ tlist,
    _Float16* __restrict__ Xg) {
  int r = blockIdx.x;
  if (r >= *total) return;
  int e = 0;
  while (e < E - 1 && r >= base[e] + pc[e]) ++e;
  int local = r - base[e];
  int d = threadIdx.x * 4;
  union { _Float16 h[4]; ushort4 u; } o;
  if (local < counts[e]) {
    int t = tlist[e * T + local];
    float4 v = *(const float4*)(x + (size_t)t * D + d);
    o.h[0] = (_Float16)v.x; o.h[1] = (_Float16)v.y;
    o.h[2] = (_Float16)v.z; o.h[3] = (_Float16)v.w;
  } else {
    o.h[0] = (_Float16)0.f; o.h[1] = (_Float16)0.f;
    o.h[2] = (_Float16)0.f; o.h[3] = (_Float16)0.f;
  }
  *(ushort4*)(Xg + (size_t)r * D + d) = o.u;
}

// ---------------- transpose-convert: [E][R][C] f32 -> [E][C][R] f16 ----------------
__global__ __launch_bounds__(256) void k_transpose(
    const float* __restrict__ src, _Float16* __restrict__ dst, int R, int C) {
  __shared__ float tile[32][33];
  int e = blockIdx.z, rt = blockIdx.y, ct = blockIdx.x;
  int tr  = threadIdx.x >> 3;
  int tc4 = (threadIdx.x & 7) * 4;
  const float* s = src + ((size_t)e * R + rt * 32 + tr) * C + ct * 32 + tc4;
  float4 v = *(const float4*)s;
  tile[tr][tc4 + 0] = v.x; tile[tr][tc4 + 1] = v.y;
  tile[tr][tc4 + 2] = v.z; tile[tr][tc4 + 3] = v.w;
  __syncthreads();
  union { _Float16 h[4]; ushort4 u; } o;
  #pragma unroll
  for (int i = 0; i < 4; ++i) o.h[i] = (_Float16)tile[tc4 + i][tr];
  *(ushort4*)(dst + ((size_t)e * C + ct * 32 + tr) * R + rt * 32 + tc4) = o.u;
}

// ---------------- fused gate+up grouped GEMM + SiLU (m97 structure) ----------------
// block tile 128 rows x 128 cols (x2 gemms), wave tile 64x64, 16x16x32 MFMA,
// flat k-major LDS [128][32] fp16, global_load_lds width-16 staging.
__global__ __launch_bounds__(256, 2) void k_upgate(
    const _Float16* __restrict__ Xg, const _Float16* __restrict__ wgT,
    const _Float16* __restrict__ wuT, _Float16* __restrict__ Hid,
    const int* __restrict__ base, const int* __restrict__ pc) {
  int e = blockIdx.z, mt = blockIdx.y, nt = blockIdx.x;
  if (mt * TM >= pc[e]) return;
  int row0 = base[e] + mt * TM;
  int n0 = nt * TN;
  __shared__ _Float16 As[TM * BK];
  __shared__ _Float16 Bg[TN * BK];
  __shared__ _Float16 Bu[TN * BK];
  int tid = threadIdx.x;
  int w = tid >> 6, lane = tid & 63;
  int lrow = lane & 15, quad = lane >> 4;
  int wr = w >> 1, wc = w & 1;            // wave grid 2x2
  int sr = lane >> 2, sc = (lane & 3) * 8; // staging: 16 rows x 64B per slot

  const _Float16* wg_e = wgT + (size_t)e * M * D;
  const _Float16* wu_e = wuT + (size_t)e * M * D;
  // per-thread global pointers (advance by BK each iter)
  const _Float16* pA0 = Xg + (size_t)(row0 + w * 32 + sr) * D + sc;
  const _Float16* pA1 = Xg + (size_t)(row0 + w * 32 + 16 + sr) * D + sc;
  const _Float16* pG0 = wg_e + (size_t)(n0 + w * 32 + sr) * D + sc;
  const _Float16* pG1 = wg_e + (size_t)(n0 + w * 32 + 16 + sr) * D + sc;
  const _Float16* pU0 = wu_e + (size_t)(n0 + w * 32 + sr) * D + sc;
  const _Float16* pU1 = wu_e + (size_t)(n0 + w * 32 + 16 + sr) * D + sc;
  char* lA0 = (char*)As + (w * 2 + 0) * 1024;
  char* lA1 = (char*)As + (w * 2 + 1) * 1024;
  char* lG0 = (char*)Bg + (w * 2 + 0) * 1024;
  char* lG1 = (char*)Bg + (w * 2 + 1) * 1024;
  char* lU0 = (char*)Bu + (w * 2 + 0) * 1024;
  char* lU1 = (char*)Bu + (w * 2 + 1) * 1024;

  floatx4 accg[4][4] = {};   // [c][i]
  floatx4 accu[4][4] = {};

  for (int k0 = 0; k0 < D; k0 += BK) {
    gl_lds16(pA0, lA0); gl_lds16(pA1, lA1);
    gl_lds16(pG0, lG0); gl_lds16(pG1, lG1);
    gl_lds16(pU0, lU0); gl_lds16(pU1, lU1);
    pA0 += BK; pA1 += BK; pG0 += BK; pG1 += BK; pU0 += BK; pU1 += BK;
    __syncthreads();   // drains vmcnt -> LDS ready
    half8 af[4];
    #pragma unroll
    for (int i = 0; i < 4; ++i)
      af[i] = *(const half8*)&As[(wr * 64 + i * 16 + lrow) * BK + quad * 8];
    #pragma unroll
    for (int c = 0; c < 4; ++c) {
      half8 bgc = *(const half8*)&Bg[(wc * 64 + c * 16 + lrow) * BK + quad * 8];
      half8 buc = *(const half8*)&Bu[(wc * 64 + c * 16 + lrow) * BK + quad * 8];
      #pragma unroll
      for (int i = 0; i < 4; ++i) {
        accg[c][i] = __builtin_amdgcn_mfma_f32_16x16x32_f16(af[i], bgc, accg[c][i], 0, 0, 0);
        accu[c][i] = __builtin_amdgcn_mfma_f32_16x16x32_f16(af[i], buc, accu[c][i], 0, 0, 0);
      }
    }
    __syncthreads();   // all reads done before next overwrite
  }
  // epilogue: h = silu(g) * u -> fp16
  #pragma unroll
  for (int c = 0; c < 4; ++c) {
    int col = n0 + wc * 64 + c * 16 + lrow;
    #pragma unroll
    for (int i = 0; i < 4; ++i) {
      int rowb = row0 + wr * 64 + i * 16 + quad * 4;
      #pragma unroll
      for (int reg = 0; reg < 4; ++reg) {
        float g = accg[c][i][reg], u = accu[c][i][reg];
        Hid[(size_t)(rowb + reg) * M + col] = (_Float16)(g / (1.f + expf(-g)) * u);
      }
    }
  }
}

// ---------------- down grouped GEMM -> per-slot rows Yp ----------------
__global__ __launch_bounds__(256, 2) void k_down(
    const _Float16* __restrict__ Hid, const _Float16* __restrict__ wdT,
    _Float16* __restrict__ Yp,
    const int* __restrict__ base, const int* __restrict__ pc) {
  int e = blockIdx.z, mt = blockIdx.y, nt = blockIdx.x;
  if (mt * TM >= pc[e]) return;
  int row0 = base[e] + mt * TM;
  int d0 = nt * TN;
  __shared__ _Float16 As[TM * BK];
  __shared__ _Float16 Bs[TN * BK];
  int tid = threadIdx.x;
  int w = tid >> 6, lane = tid & 63;
  int lrow = lane & 15, quad = lane >> 4;
  int wr = w >> 1, wc = w & 1;
  int sr = lane >> 2, sc = (lane & 3) * 8;

  const _Float16* wd_e = wdT + (size_t)e * D * M;
  const _Float16* pA0 = Hid + (size_t)(row0 + w * 32 + sr) * M + sc;
  const _Float16* pA1 = Hid + (size_t)(row0 + w * 32 + 16 + sr) * M + sc;
  const _Float16* pB0 = wd_e + (size_t)(d0 + w * 32 + sr) * M + sc;
  const _Float16* pB1 = wd_e + (size_t)(d0 + w * 32 + 16 + sr) * M + sc;
  char* lA0 = (char*)As + (w * 2 + 0) * 1024;
  char* lA1 = (char*)As + (w * 2 + 1) * 1024;
  char* lB0 = (char*)Bs + (w * 2 + 0) * 1024;
  char* lB1 = (char*)Bs + (w * 2 + 1) * 1024;

  floatx4 acc[4][4] = {};   // [c][i]

  for (int k0 = 0; k0 < M; k0 += BK) {   // 44 iters
    gl_lds16(pA0, lA0); gl_lds16(pA1, lA1);
    gl_lds16(pB0, lB0); gl_lds16(pB1, lB1);
    pA0 += BK; pA1 += BK; pB0 += BK; pB1 += BK;
    __syncthreads();
    half8 af[4];
    #pragma unroll
    for (int i = 0; i < 4; ++i)
      af[i] = *(const half8*)&As[(wr * 64 + i * 16 + lrow) * BK + quad * 8];
    #pragma unroll
    for (int c = 0; c < 4; ++c) {
      half8 bc = *(const half8*)&Bs[(wc * 64 + c * 16 + lrow) * BK + quad * 8];
      #pragma unroll
      for (int i = 0; i < 4; ++i)
        acc[c][i] = __builtin_amdgcn_mfma_f32_16x16x32_f16(af[i], bc, acc[c][i], 0, 0, 0);
    }
    __syncthreads();
  }
  #pragma unroll
  for (int c = 0; c < 4; ++c) {
    int col = d0 + wc * 64 + c * 16 + lrow;
    #pragma unroll
    for (int i = 0; i < 4; ++i) {
      int rowb = row0 + wr * 64 + i * 16 + quad * 4;
      #pragma unroll
      for (int reg = 0; reg < 4; ++reg)
        Yp[(size_t)(rowb + reg) * D + col] = (_Float16)acc[c][i][reg];
    }
  }
}

// ---------------- combine: y[t] = p0*Yp[r0] + p1*Yp[r1] ----------------
__global__ __launch_bounds__(256) void k_combine(
    const _Float16* __restrict__ Yp, const int* __restrict__ base,
    const int* __restrict__ t2e, const int* __restrict__ t2pos,
    const float* __restrict__ t2p, float* __restrict__ out) {
  int t = blockIdx.x;
  int r0 = base[t2e[2 * t]]     + t2pos[2 * t];
  int r1 = base[t2e[2 * t + 1]] + t2pos[2 * t + 1];
  float p0 = t2p[2 * t], p1 = t2p[2 * t + 1];
  int d = threadIdx.x * 4;
  half4 h0 = *(const half4*)(Yp + (size_t)r0 * D + d);
  half4 h1 = *(const half4*)(Yp + (size_t)r1 * D + d);
  float4 o;
  o.x = p0 * (float)h0.x + p1 * (float)h1.x;
  o.y = p0 * (float)h0.y + p1 * (float)h1.y;
  o.z = p0 * (float)h0.z + p1 * (float)h1.z;
  o.w = p0 * (float)h0.w + p1 * (float)h1.w;
  *(float4*)(out + (size_t)t * D + d) = o;
}

// ---------------- launch ----------------
extern "C" void kernel_launch(void* const* d_in, const int* in_sizes, int n_in,
                              void* d_out, int out_size, void* d_ws, size_t ws_size,
                              hipStream_t stream) {
  const float* x     = (const float*)d_in[0];
  const float* wgate = (const float*)d_in[1];
  const float* w_g   = (const float*)d_in[2];
  const float* w_u   = (const float*)d_in[3];
  const float* w_d   = (const float*)d_in[4];
  float* out = (float*)d_out;
  char* ws = (char*)d_ws;

  if (ws_size < WS_NEED) {
    fprintf(stderr, "kernel_launch: ws_size=%zu < needed %zu\n", ws_size, WS_NEED);
    return;
  }

  int* counts = (int*)(ws + OFF_COUNTS);
  int* base   = (int*)(ws + OFF_BASE);
  int* pcn    = (int*)(ws + OFF_PC);
  int* total  = (int*)(ws + OFF_TOTAL);
  int* t2e    = (int*)(ws + OFF_T2E);
  int* t2pos  = (int*)(ws + OFF_T2POS);
  float* t2p  = (float*)(ws + OFF_T2P);
  int* tlist  = (int*)(ws + OFF_TLIST);
  _Float16* Xg  = (_Float16*)(ws + OFF_XG);   // later reused as Yp
  _Float16* Hid = (_Float16*)(ws + OFF_HID);
  _Float16* wgT = (_Float16*)(ws + OFF_WGT);
  _Float16* wuT = (_Float16*)(ws + OFF_WUT);
  _Float16* wdT = (_Float16*)(ws + OFF_WDT);

  hipMemsetAsync(ws, 0, 256, stream);   // counts/base/pc/total

  k_router<<<T / 4, 256, 0, stream>>>(x, wgate, counts, tlist, t2e, t2pos, t2p);
  k_scan<<<1, 64, 0, stream>>>(counts, base, pcn, total);
  k_gather<<<RCAP, 256, 0, stream>>>(x, counts, base, pcn, total, tlist, Xg);

  k_transpose<<<dim3(M / 32, D / 32, E), 256, 0, stream>>>(w_g, wgT, D, M);
  k_transpose<<<dim3(M / 32, D / 32, E), 256, 0, stream>>>(w_u, wuT, D, M);
  k_transpose<<<dim3(D / 32, M / 32, E), 256, 0, stream>>>(w_d, wdT, M, D);

  k_upgate<<<dim3(M / TN, T / TM, E), 256, 0, stream>>>(Xg, wgT, wuT, Hid, base, pcn);
  // Xg is dead now; reuse its storage as Yp
  _Float16* Yp = Xg;
  k_down<<<dim3(D / TN, T / TM, E), 256, 0, stream>>>(Hid, wdT, Yp, base, pcn);
  k_combine<<<T, 256, 0, stream>>>(Yp, base, t2e, t2pos, t2p, out);
}

// Round 3
// 389.530 us; speedup vs baseline: 1.1755x; 1.1461x over previous
//
#include <hip/hip_runtime.h>
#include <cstdio>

// ---------------- problem constants ----------------
constexpr int T  = 4096;       // B*S tokens
constexpr int D  = 1024;       // n_embed
constexpr int M  = 1408;       // n_moe_mlp
constexpr int E  = 8;          // experts

constexpr int TM = 128;        // token-rows per tile
constexpr int TN = 128;        // output cols per tile
constexpr int BK = 32;         // K-step
constexpr int RCAP = T * 2 + E * TM;  // 9216 padded row capacity

constexpr int CSTR = 64;       // per-expert counter stride in ints (256 B) — de-alias cache lines
constexpr int TOKB = 64;       // tokens per router block

typedef _Float16 half8 __attribute__((ext_vector_type(8)));
typedef _Float16 half4 __attribute__((ext_vector_type(4)));
typedef float    floatx4 __attribute__((ext_vector_type(4)));

// ---------------- ws layout (bytes) ----------------
constexpr size_t OFF_COUNTS = 0;                               // E*CSTR ints (padded counters)
constexpr size_t OFF_BASE   = (size_t)E * CSTR * 4;            // E ints
constexpr size_t OFF_PC     = OFF_BASE + 64;                   // E ints
constexpr size_t OFF_TOTAL  = OFF_PC + 64;                     // 1 int
constexpr size_t OFF_T2E    = OFF_TOTAL + 64;                  // 2T ints
constexpr size_t OFF_T2POS  = OFF_T2E   + (size_t)2 * T * 4;
constexpr size_t OFF_T2P    = OFF_T2POS + (size_t)2 * T * 4;
constexpr size_t OFF_TLIST  = OFF_T2P   + (size_t)2 * T * 4;   // E*T ints
constexpr size_t OFF_XG     = OFF_TLIST + (size_t)E * T * 4;   // RCAP x D fp16 (reused as Yp)
constexpr size_t OFF_HID    = OFF_XG  + (size_t)RCAP * D * 2;  // RCAP x M fp16
constexpr size_t OFF_WGT    = OFF_HID + (size_t)RCAP * M * 2;  // E x M x D fp16
constexpr size_t OFF_WUT    = OFF_WGT + (size_t)E * M * D * 2;
constexpr size_t OFF_WDT    = OFF_WUT + (size_t)E * M * D * 2; // E x D x M fp16
constexpr size_t WS_NEED    = OFF_WDT + (size_t)E * D * M * 2;

// async global->LDS, 16B per lane. LDS dest = wave-uniform base + lane*16.
__device__ __forceinline__ void gl_lds16(const void* g, void* l) {
  __builtin_amdgcn_global_load_lds(
      (const __attribute__((address_space(1))) unsigned int*)g,
      (__attribute__((address_space(3))) unsigned int*)l, 16, 0, 0);
}

// ---------------- router: 64 tokens/block, LDS-aggregated positions ----------------
__global__ __launch_bounds__(256) void k_router(
    const float* __restrict__ x, const float* __restrict__ wgate,
    int* __restrict__ counts, int* __restrict__ tlist,
    int* __restrict__ t2e, int* __restrict__ t2pos, float* __restrict__ t2p) {
  __shared__ int   s_cnt[E];
  __shared__ int   s_base[E];
  __shared__ int   s_e[2 * TOKB];
  __shared__ int   s_pos[2 * TOKB];
  __shared__ float s_p[2 * TOKB];
  int wv = threadIdx.x >> 6, lane = threadIdx.x & 63;
  if (threadIdx.x < E) s_cnt[threadIdx.x] = 0;
  __syncthreads();

  for (int j = 0; j < TOKB / 4; ++j) {         // 16 tokens per wave
    int tl = wv * (TOKB / 4) + j;
    int t  = blockIdx.x * TOKB + tl;
    const float* xr = x + (size_t)t * D;
    float acc[E] = {0.f,0.f,0.f,0.f,0.f,0.f,0.f,0.f};
    #pragma unroll
    for (int i = 0; i < D / 64; ++i) {
      int d = i * 64 + lane;
      float xv = xr[d];
      const float4* wr2 = (const float4*)(wgate + (size_t)d * E);
      float4 w0 = wr2[0], w1 = wr2[1];
      acc[0] += xv * w0.x; acc[1] += xv * w0.y; acc[2] += xv * w0.z; acc[3] += xv * w0.w;
      acc[4] += xv * w1.x; acc[5] += xv * w1.y; acc[6] += xv * w1.z; acc[7] += xv * w1.w;
    }
    #pragma unroll
    for (int e = 0; e < E; ++e) {
      #pragma unroll
      for (int off = 32; off; off >>= 1) acc[e] += __shfl_xor(acc[e], off, 64);
    }
    if (lane == 0) {
      int i0 = 0; float s0 = acc[0];
      #pragma unroll
      for (int e = 1; e < E; ++e) if (acc[e] > s0) { s0 = acc[e]; i0 = e; }
      int i1 = -1; float s1 = -1e30f;
      #pragma unroll
      for (int e = 0; e < E; ++e) if (e != i0 && acc[e] > s1) { s1 = acc[e]; i1 = e; }
      float p0 = 1.f / (1.f + expf(s1 - s0));   // stable 2-way softmax (s0 >= s1)
      float p1 = 1.f - p0;
      int q0 = atomicAdd(&s_cnt[i0], 1);        // LDS atomics — on-CU, fast
      int q1 = atomicAdd(&s_cnt[i1], 1);
      s_e[2 * tl]     = i0; s_pos[2 * tl]     = q0; s_p[2 * tl]     = p0;
      s_e[2 * tl + 1] = i1; s_pos[2 * tl + 1] = q1; s_p[2 * tl + 1] = p1;
    }
  }
  __syncthreads();
  // one global atomic per expert per block (8 per block, 512 total, de-aliased lines)
  if (threadIdx.x < E)
    s_base[threadIdx.x] = atomicAdd(&counts[threadIdx.x * CSTR], s_cnt[threadIdx.x]);
  __syncthreads();
  if (threadIdx.x < 2 * TOKB) {
    int sl = threadIdx.x;
    int e = s_e[sl];
    int pos = s_base[e] + s_pos[sl];
    int t = blockIdx.x * TOKB + (sl >> 1);
    tlist[e * T + pos] = t;
    t2e[2 * t + (sl & 1)]   = e;
    t2pos[2 * t + (sl & 1)] = pos;
    t2p[2 * t + (sl & 1)]   = s_p[sl];
  }
}

// ---------------- scan ----------------
__global__ void k_scan(const int* __restrict__ counts, int* __restrict__ base,
                       int* __restrict__ pc, int* __restrict__ total) {
  if (threadIdx.x == 0 && blockIdx.x == 0) {
    int b = 0;
    for (int e = 0; e < E; ++e) {
      base[e] = b;
      int p = (counts[e * CSTR] + TM - 1) / TM * TM;
      pc[e] = p; b += p;
    }
    *total = b;
  }
}

// ---------------- gather tokens -> fp16, zero pad rows ----------------
__global__ __launch_bounds__(256) void k_gather(
    const float* __restrict__ x, const int* __restrict__ counts,
    const int* __restrict__ base, const int* __restrict__ pc,
    const int* __restrict__ total, const int* __restrict__ tlist,
    _Float16* __restrict__ Xg) {
  int r = blockIdx.x;
  if (r >= *total) return;
  int e = 0;
  while (e < E - 1 && r >= base[e] + pc[e]) ++e;
  int local = r - base[e];
  int d = threadIdx.x * 4;
  union { _Float16 h[4]; ushort4 u; } o;
  if (local < counts[e * CSTR]) {
    int t = tlist[e * T + local];
    float4 v = *(const float4*)(x + (size_t)t * D + d);
    o.h[0] = (_Float16)v.x; o.h[1] = (_Float16)v.y;
    o.h[2] = (_Float16)v.z; o.h[3] = (_Float16)v.w;
  } else {
    o.h[0] = (_Float16)0.f; o.h[1] = (_Float16)0.f;
    o.h[2] = (_Float16)0.f; o.h[3] = (_Float16)0.f;
  }
  *(ushort4*)(Xg + (size_t)r * D + d) = o.u;
}

// ---------------- transpose-convert: [E][R][C] f32 -> [E][C][R] f16 ----------------
__global__ __launch_bounds__(256) void k_transpose(
    const float* __restrict__ src, _Float16* __restrict__ dst, int R, int C) {
  __shared__ float tile[32][33];
  int e = blockIdx.z, rt = blockIdx.y, ct = blockIdx.x;
  int tr  = threadIdx.x >> 3;
  int tc4 = (threadIdx.x & 7) * 4;
  const float* s = src + ((size_t)e * R + rt * 32 + tr) * C + ct * 32 + tc4;
  float4 v = *(const float4*)s;
  tile[tr][tc4 + 0] = v.x; tile[tr][tc4 + 1] = v.y;
  tile[tr][tc4 + 2] = v.z; tile[tr][tc4 + 3] = v.w;
  __syncthreads();
  union { _Float16 h[4]; ushort4 u; } o;
  #pragma unroll
  for (int i = 0; i < 4; ++i) o.h[i] = (_Float16)tile[tc4 + i][tr];
  *(ushort4*)(dst + ((size_t)e * C + ct * 32 + tr) * R + rt * 32 + tc4) = o.u;
}

// ---------------- fused gate+up grouped GEMM + SiLU (m97 structure) ----------------
__global__ __launch_bounds__(256, 2) void k_upgate(
    const _Float16* __restrict__ Xg, const _Float16* __restrict__ wgT,
    const _Float16* __restrict__ wuT, _Float16* __restrict__ Hid,
    const int* __restrict__ base, const int* __restrict__ pc) {
  int e = blockIdx.z, mt = blockIdx.y, nt = blockIdx.x;
  if (mt * TM >= pc[e]) return;
  int row0 = base[e] + mt * TM;
  int n0 = nt * TN;
  __shared__ _Float16 As[TM * BK];
  __shared__ _Float16 Bg[TN * BK];
  __shared__ _Float16 Bu[TN * BK];
  int tid = threadIdx.x;
  int w = tid >> 6, lane = tid & 63;
  int lrow = lane & 15, quad = lane >> 4;
  int wr = w >> 1, wc = w & 1;            // wave grid 2x2
  int sr = lane >> 2, sc = (lane & 3) * 8; // staging: 16 rows x 64B per slot

  const _Float16* wg_e = wgT + (size_t)e * M * D;
  const _Float16* wu_e = wuT + (size_t)e * M * D;
  const _Float16* pA0 = Xg + (size_t)(row0 + w * 32 + sr) * D + sc;
  const _Float16* pA1 = Xg + (size_t)(row0 + w * 32 + 16 + sr) * D + sc;
  const _Float16* pG0 = wg_e + (size_t)(n0 + w * 32 + sr) * D + sc;
  const _Float16* pG1 = wg_e + (size_t)(n0 + w * 32 + 16 + sr) * D + sc;
  const _Float16* pU0 = wu_e + (size_t)(n0 + w * 32 + sr) * D + sc;
  const _Float16* pU1 = wu_e + (size_t)(n0 + w * 32 + 16 + sr) * D + sc;
  char* lA0 = (char*)As + (w * 2 + 0) * 1024;
  char* lA1 = (char*)As + (w * 2 + 1) * 1024;
  char* lG0 = (char*)Bg + (w * 2 + 0) * 1024;
  char* lG1 = (char*)Bg + (w * 2 + 1) * 1024;
  char* lU0 = (char*)Bu + (w * 2 + 0) * 1024;
  char* lU1 = (char*)Bu + (w * 2 + 1) * 1024;

  floatx4 accg[4][4] = {};   // [c][i]
  floatx4 accu[4][4] = {};

  for (int k0 = 0; k0 < D; k0 += BK) {
    gl_lds16(pA0, lA0); gl_lds16(pA1, lA1);
    gl_lds16(pG0, lG0); gl_lds16(pG1, lG1);
    gl_lds16(pU0, lU0); gl_lds16(pU1, lU1);
    pA0 += BK; pA1 += BK; pG0 += BK; pG1 += BK; pU0 += BK; pU1 += BK;
    __syncthreads();
    half8 af[4];
    #pragma unroll
    for (int i = 0; i < 4; ++i)
      af[i] = *(const half8*)&As[(wr * 64 + i * 16 + lrow) * BK + quad * 8];
    #pragma unroll
    for (int c = 0; c < 4; ++c) {
      half8 bgc = *(const half8*)&Bg[(wc * 64 + c * 16 + lrow) * BK + quad * 8];
      half8 buc = *(const half8*)&Bu[(wc * 64 + c * 16 + lrow) * BK + quad * 8];
      #pragma unroll
      for (int i = 0; i < 4; ++i) {
        accg[c][i] = __builtin_amdgcn_mfma_f32_16x16x32_f16(af[i], bgc, accg[c][i], 0, 0, 0);
        accu[c][i] = __builtin_amdgcn_mfma_f32_16x16x32_f16(af[i], buc, accu[c][i], 0, 0, 0);
      }
    }
    __syncthreads();
  }
  #pragma unroll
  for (int c = 0; c < 4; ++c) {
    int col = n0 + wc * 64 + c * 16 + lrow;
    #pragma unroll
    for (int i = 0; i < 4; ++i) {
      int rowb = row0 + wr * 64 + i * 16 + quad * 4;
      #pragma unroll
      for (int reg = 0; reg < 4; ++reg) {
        float g = accg[c][i][reg], u = accu[c][i][reg];
        Hid[(size_t)(rowb + reg) * M + col] = (_Float16)(g / (1.f + expf(-g)) * u);
      }
    }
  }
}

// ---------------- down grouped GEMM -> per-slot rows Yp ----------------
__global__ __launch_bounds__(256, 2) void k_down(
    const _Float16* __restrict__ Hid, const _Float16* __restrict__ wdT,
    _Float16* __restrict__ Yp,
    const int* __restrict__ base, const int* __restrict__ pc) {
  int e = blockIdx.z, mt = blockIdx.y, nt = blockIdx.x;
  if (mt * TM >= pc[e]) return;
  int row0 = base[e] + mt * TM;
  int d0 = nt * TN;
  __shared__ _Float16 As[TM * BK];
  __shared__ _Float16 Bs[TN * BK];
  int tid = threadIdx.x;
  int w = tid >> 6, lane = tid & 63;
  int lrow = lane & 15, quad = lane >> 4;
  int wr = w >> 1, wc = w & 1;
  int sr = lane >> 2, sc = (lane & 3) * 8;

  const _Float16* wd_e = wdT + (size_t)e * D * M;
  const _Float16* pA0 = Hid + (size_t)(row0 + w * 32 + sr) * M + sc;
  const _Float16* pA1 = Hid + (size_t)(row0 + w * 32 + 16 + sr) * M + sc;
  const _Float16* pB0 = wd_e + (size_t)(d0 + w * 32 + sr) * M + sc;
  const _Float16* pB1 = wd_e + (size_t)(d0 + w * 32 + 16 + sr) * M + sc;
  char* lA0 = (char*)As + (w * 2 + 0) * 1024;
  char* lA1 = (char*)As + (w * 2 + 1) * 1024;
  char* lB0 = (char*)Bs + (w * 2 + 0) * 1024;
  char* lB1 = (char*)Bs + (w * 2 + 1) * 1024;

  floatx4 acc[4][4] = {};

  for (int k0 = 0; k0 < M; k0 += BK) {
    gl_lds16(pA0, lA0); gl_lds16(pA1, lA1);
    gl_lds16(pB0, lB0); gl_lds16(pB1, lB1);
    pA0 += BK; pA1 += BK; pB0 += BK; pB1 += BK;
    __syncthreads();
    half8 af[4];
    #pragma unroll
    for (int i = 0; i < 4; ++i)
      af[i] = *(const half8*)&As[(wr * 64 + i * 16 + lrow) * BK + quad * 8];
    #pragma unroll
    for (int c = 0; c < 4; ++c) {
      half8 bc = *(const half8*)&Bs[(wc * 64 + c * 16 + lrow) * BK + quad * 8];
      #pragma unroll
      for (int i = 0; i < 4; ++i)
        acc[c][i] = __builtin_amdgcn_mfma_f32_16x16x32_f16(af[i], bc, acc[c][i], 0, 0, 0);
    }
    __syncthreads();
  }
  #pragma unroll
  for (int c = 0; c < 4; ++c) {
    int col = d0 + wc * 64 + c * 16 + lrow;
    #pragma unroll
    for (int i = 0; i < 4; ++i) {
      int rowb = row0 + wr * 64 + i * 16 + quad * 4;
      #pragma unroll
      for (int reg = 0; reg < 4; ++reg)
        Yp[(size_t)(rowb + reg) * D + col] = (_Float16)acc[c][i][reg];
    }
  }
}

// ---------------- combine: y[t] = p0*Yp[r0] + p1*Yp[r1] ----------------
__global__ __launch_bounds__(256) void k_combine(
    const _Float16* __restrict__ Yp, const int* __restrict__ base,
    const int* __restrict__ t2e, const int* __restrict__ t2pos,
    const float* __restrict__ t2p, float* __restrict__ out) {
  int t = blockIdx.x;
  int r0 = base[t2e[2 * t]]     + t2pos[2 * t];
  int r1 = base[t2e[2 * t + 1]] + t2pos[2 * t + 1];
  float p0 = t2p[2 * t], p1 = t2p[2 * t + 1];
  int d = threadIdx.x * 4;
  half4 h0 = *(const half4*)(Yp + (size_t)r0 * D + d);
  half4 h1 = *(const half4*)(Yp + (size_t)r1 * D + d);
  float4 o;
  o.x = p0 * (float)h0.x + p1 * (float)h1.x;
  o.y = p0 * (float)h0.y + p1 * (float)h1.y;
  o.z = p0 * (float)h0.z + p1 * (float)h1.z;
  o.w = p0 * (float)h0.w + p1 * (float)h1.w;
  *(float4*)(out + (size_t)t * D + d) = o;
}

// ---------------- launch ----------------
extern "C" void kernel_launch(void* const* d_in, const int* in_sizes, int n_in,
                              void* d_out, int out_size, void* d_ws, size_t ws_size,
                              hipStream_t stream) {
  const float* x     = (const float*)d_in[0];
  const float* wgate = (const float*)d_in[1];
  const float* w_g   = (const float*)d_in[2];
  const float* w_u   = (const float*)d_in[3];
  const float* w_d   = (const float*)d_in[4];
  float* out = (float*)d_out;
  char* ws = (char*)d_ws;

  if (ws_size < WS_NEED) {
    fprintf(stderr, "kernel_launch: ws_size=%zu < needed %zu\n", ws_size, WS_NEED);
    return;
  }

  int* counts = (int*)(ws + OFF_COUNTS);
  int* base   = (int*)(ws + OFF_BASE);
  int* pcn    = (int*)(ws + OFF_PC);
  int* total  = (int*)(ws + OFF_TOTAL);
  int* t2e    = (int*)(ws + OFF_T2E);
  int* t2pos  = (int*)(ws + OFF_T2POS);
  float* t2p  = (float*)(ws + OFF_T2P);
  int* tlist  = (int*)(ws + OFF_TLIST);
  _Float16* Xg  = (_Float16*)(ws + OFF_XG);   // later reused as Yp
  _Float16* Hid = (_Float16*)(ws + OFF_HID);
  _Float16* wgT = (_Float16*)(ws + OFF_WGT);
  _Float16* wuT = (_Float16*)(ws + OFF_WUT);
  _Float16* wdT = (_Float16*)(ws + OFF_WDT);

  hipMemsetAsync(ws, 0, OFF_T2E, stream);   // zero padded counters (+base/pc/total)

  k_router<<<T / TOKB, 256, 0, stream>>>(x, wgate, counts, tlist, t2e, t2pos, t2p);
  k_scan<<<1, 64, 0, stream>>>(counts, base, pcn, total);
  k_gather<<<RCAP, 256, 0, stream>>>(x, counts, base, pcn, total, tlist, Xg);

  k_transpose<<<dim3(M / 32, D / 32, E), 256, 0, stream>>>(w_g, wgT, D, M);
  k_transpose<<<dim3(M / 32, D / 32, E), 256, 0, stream>>>(w_u, wuT, D, M);
  k_transpose<<<dim3(D / 32, M / 32, E), 256, 0, stream>>>(w_d, wdT, M, D);

  k_upgate<<<dim3(M / TN, T / TM, E), 256, 0, stream>>>(Xg, wgT, wuT, Hid, base, pcn);
  _Float16* Yp = Xg;   // Xg dead; reuse as Yp
  k_down<<<dim3(D / TN, T / TM, E), 256, 0, stream>>>(Hid, wdT, Yp, base, pcn);
  k_combine<<<T, 256, 0, stream>>>(Yp, base, t2e, t2pos, t2p, out);
}

// Round 4
// 346.058 us; speedup vs baseline: 1.3232x; 1.1256x over previous
//
#include <hip/hip_runtime.h>
#include <cstdio>

// ---------------- problem constants ----------------
constexpr int T  = 4096;       // B*S tokens
constexpr int D  = 1024;       // n_embed
constexpr int M  = 1408;       // n_moe_mlp
constexpr int E  = 8;          // experts

constexpr int TM = 128;        // token-rows per tile
constexpr int TN = 128;        // output cols per tile
constexpr int BK = 32;         // K-step
constexpr int RCAP = T * 2 + E * TM;  // 9216 padded row capacity
constexpr int MT_MAX = T / TM; // 32 row-tiles max per expert
constexpr int NT_UP = M / TN;  // 11
constexpr int NT_DN = D / TN;  // 8

constexpr int CSTR = 64;       // per-expert counter stride in ints (256 B)
constexpr int TOKB = 64;       // tokens per router block

typedef _Float16 half8 __attribute__((ext_vector_type(8)));
typedef _Float16 half4 __attribute__((ext_vector_type(4)));
typedef float    floatx4 __attribute__((ext_vector_type(4)));

// ---------------- ws layout (bytes) ----------------
constexpr size_t OFF_COUNTS = 0;                               // E*CSTR ints
constexpr size_t OFF_BASE   = (size_t)E * CSTR * 4;            // E ints
constexpr size_t OFF_PC     = OFF_BASE + 64;                   // E ints
constexpr size_t OFF_TOTAL  = OFF_PC + 64;                     // 1 int
constexpr size_t OFF_T2E    = OFF_TOTAL + 64;                  // 2T ints
constexpr size_t OFF_T2POS  = OFF_T2E   + (size_t)2 * T * 4;
constexpr size_t OFF_T2P    = OFF_T2POS + (size_t)2 * T * 4;
constexpr size_t OFF_TLIST  = OFF_T2P   + (size_t)2 * T * 4;   // E*T ints
constexpr size_t OFF_XG     = OFF_TLIST + (size_t)E * T * 4;   // RCAP x D fp16 (reused as Yp)
constexpr size_t OFF_HID    = OFF_XG  + (size_t)RCAP * D * 2;  // RCAP x M fp16
constexpr size_t OFF_WGT    = OFF_HID + (size_t)RCAP * M * 2;  // E x M x D fp16
constexpr size_t OFF_WUT    = OFF_WGT + (size_t)E * M * D * 2;
constexpr size_t OFF_WDT    = OFF_WUT + (size_t)E * M * D * 2; // E x D x M fp16
constexpr size_t WS_NEED    = OFF_WDT + (size_t)E * D * M * 2;

// async global->LDS, 16B per lane. LDS dest = wave-uniform base + lane*16.
__device__ __forceinline__ void gl_lds16(const void* g, void* l) {
  __builtin_amdgcn_global_load_lds(
      (const __attribute__((address_space(1))) unsigned int*)g,
      (__attribute__((address_space(3))) unsigned int*)l, 16, 0, 0);
}

// ---------------- router: 64 tokens/block, LDS-aggregated positions ----------------
__global__ __launch_bounds__(256) void k_router(
    const float* __restrict__ x, const float* __restrict__ wgate,
    int* __restrict__ counts, int* __restrict__ tlist,
    int* __restrict__ t2e, int* __restrict__ t2pos, float* __restrict__ t2p) {
  __shared__ int   s_cnt[E];
  __shared__ int   s_base[E];
  __shared__ int   s_e[2 * TOKB];
  __shared__ int   s_pos[2 * TOKB];
  __shared__ float s_p[2 * TOKB];
  int wv = threadIdx.x >> 6, lane = threadIdx.x & 63;
  if (threadIdx.x < E) s_cnt[threadIdx.x] = 0;
  __syncthreads();

  for (int j = 0; j < TOKB / 4; ++j) {
    int tl = wv * (TOKB / 4) + j;
    int t  = blockIdx.x * TOKB + tl;
    const float* xr = x + (size_t)t * D;
    float acc[E] = {0.f,0.f,0.f,0.f,0.f,0.f,0.f,0.f};
    #pragma unroll
    for (int i = 0; i < D / 64; ++i) {
      int d = i * 64 + lane;
      float xv = xr[d];
      const float4* wr2 = (const float4*)(wgate + (size_t)d * E);
      float4 w0 = wr2[0], w1 = wr2[1];
      acc[0] += xv * w0.x; acc[1] += xv * w0.y; acc[2] += xv * w0.z; acc[3] += xv * w0.w;
      acc[4] += xv * w1.x; acc[5] += xv * w1.y; acc[6] += xv * w1.z; acc[7] += xv * w1.w;
    }
    #pragma unroll
    for (int e = 0; e < E; ++e) {
      #pragma unroll
      for (int off = 32; off; off >>= 1) acc[e] += __shfl_xor(acc[e], off, 64);
    }
    if (lane == 0) {
      int i0 = 0; float s0 = acc[0];
      #pragma unroll
      for (int e = 1; e < E; ++e) if (acc[e] > s0) { s0 = acc[e]; i0 = e; }
      int i1 = -1; float s1 = -1e30f;
      #pragma unroll
      for (int e = 0; e < E; ++e) if (e != i0 && acc[e] > s1) { s1 = acc[e]; i1 = e; }
      float p0 = 1.f / (1.f + expf(s1 - s0));
      float p1 = 1.f - p0;
      int q0 = atomicAdd(&s_cnt[i0], 1);
      int q1 = atomicAdd(&s_cnt[i1], 1);
      s_e[2 * tl]     = i0; s_pos[2 * tl]     = q0; s_p[2 * tl]     = p0;
      s_e[2 * tl + 1] = i1; s_pos[2 * tl + 1] = q1; s_p[2 * tl + 1] = p1;
    }
  }
  __syncthreads();
  if (threadIdx.x < E)
    s_base[threadIdx.x] = atomicAdd(&counts[threadIdx.x * CSTR], s_cnt[threadIdx.x]);
  __syncthreads();
  if (threadIdx.x < 2 * TOKB) {
    int sl = threadIdx.x;
    int e = s_e[sl];
    int pos = s_base[e] + s_pos[sl];
    int t = blockIdx.x * TOKB + (sl >> 1);
    tlist[e * T + pos] = t;
    t2e[2 * t + (sl & 1)]   = e;
    t2pos[2 * t + (sl & 1)] = pos;
    t2p[2 * t + (sl & 1)]   = s_p[sl];
  }
}

// ---------------- scan ----------------
__global__ void k_scan(const int* __restrict__ counts, int* __restrict__ base,
                       int* __restrict__ pc, int* __restrict__ total) {
  if (threadIdx.x == 0 && blockIdx.x == 0) {
    int b = 0;
    for (int e = 0; e < E; ++e) {
      base[e] = b;
      int p = (counts[e * CSTR] + TM - 1) / TM * TM;
      pc[e] = p; b += p;
    }
    *total = b;
  }
}

// ---------------- gather tokens -> fp16, zero pad rows ----------------
__global__ __launch_bounds__(256) void k_gather(
    const float* __restrict__ x, const int* __restrict__ counts,
    const int* __restrict__ base, const int* __restrict__ pc,
    const int* __restrict__ total, const int* __restrict__ tlist,
    _Float16* __restrict__ Xg) {
  int r = blockIdx.x;
  if (r >= *total) return;
  int e = 0;
  while (e < E - 1 && r >= base[e] + pc[e]) ++e;
  int local = r - base[e];
  int d = threadIdx.x * 4;
  union { _Float16 h[4]; ushort4 u; } o;
  if (local < counts[e * CSTR]) {
    int t = tlist[e * T + local];
    float4 v = *(const float4*)(x + (size_t)t * D + d);
    o.h[0] = (_Float16)v.x; o.h[1] = (_Float16)v.y;
    o.h[2] = (_Float16)v.z; o.h[3] = (_Float16)v.w;
  } else {
    o.h[0] = (_Float16)0.f; o.h[1] = (_Float16)0.f;
    o.h[2] = (_Float16)0.f; o.h[3] = (_Float16)0.f;
  }
  *(ushort4*)(Xg + (size_t)r * D + d) = o.u;
}

// ---------------- transpose-convert: [E][R][C] f32 -> [E][C][R] f16 ----------------
__global__ __launch_bounds__(256) void k_transpose(
    const float* __restrict__ src, _Float16* __restrict__ dst, int R, int C) {
  __shared__ float tile[32][33];
  int e = blockIdx.z, rt = blockIdx.y, ct = blockIdx.x;
  int tr  = threadIdx.x >> 3;
  int tc4 = (threadIdx.x & 7) * 4;
  const float* s = src + ((size_t)e * R + rt * 32 + tr) * C + ct * 32 + tc4;
  float4 v = *(const float4*)s;
  tile[tr][tc4 + 0] = v.x; tile[tr][tc4 + 1] = v.y;
  tile[tr][tc4 + 2] = v.z; tile[tr][tc4 + 3] = v.w;
  __syncthreads();
  union { _Float16 h[4]; ushort4 u; } o;
  #pragma unroll
  for (int i = 0; i < 4; ++i) o.h[i] = (_Float16)tile[tc4 + i][tr];
  *(ushort4*)(dst + ((size_t)e * C + ct * 32 + tr) * R + rt * 32 + tc4) = o.u;
}

// ---------------- fused gate+up grouped GEMM + SiLU ----------------
// 1-D grid; e = blockIdx.x & 7 pins each expert to one XCD (sequential
// round-robin dispatch) so its weights stay resident in that XCD's L2.
__global__ __launch_bounds__(256, 2) void k_upgate(
    const _Float16* __restrict__ Xg, const _Float16* __restrict__ wgT,
    const _Float16* __restrict__ wuT, _Float16* __restrict__ Hid,
    const int* __restrict__ base, const int* __restrict__ pc) {
  int lin = blockIdx.x;
  int e = lin & 7;
  int r = lin >> 3;
  int nt = r % NT_UP;        // nt cycles fastest -> concurrent blocks share A/B tiles in L2
  int mt = r / NT_UP;
  if (mt * TM >= pc[e]) return;
  int row0 = base[e] + mt * TM;
  int n0 = nt * TN;
  __shared__ _Float16 As[TM * BK];
  __shared__ _Float16 Bg[TN * BK];
  __shared__ _Float16 Bu[TN * BK];
  int tid = threadIdx.x;
  int w = tid >> 6, lane = tid & 63;
  int lrow = lane & 15, quad = lane >> 4;
  int wr = w >> 1, wc = w & 1;
  int sr = lane >> 2, sc = (lane & 3) * 8;

  const _Float16* wg_e = wgT + (size_t)e * M * D;
  const _Float16* wu_e = wuT + (size_t)e * M * D;
  const _Float16* pA0 = Xg + (size_t)(row0 + w * 32 + sr) * D + sc;
  const _Float16* pA1 = Xg + (size_t)(row0 + w * 32 + 16 + sr) * D + sc;
  const _Float16* pG0 = wg_e + (size_t)(n0 + w * 32 + sr) * D + sc;
  const _Float16* pG1 = wg_e + (size_t)(n0 + w * 32 + 16 + sr) * D + sc;
  const _Float16* pU0 = wu_e + (size_t)(n0 + w * 32 + sr) * D + sc;
  const _Float16* pU1 = wu_e + (size_t)(n0 + w * 32 + 16 + sr) * D + sc;
  char* lA0 = (char*)As + (w * 2 + 0) * 1024;
  char* lA1 = (char*)As + (w * 2 + 1) * 1024;
  char* lG0 = (char*)Bg + (w * 2 + 0) * 1024;
  char* lG1 = (char*)Bg + (w * 2 + 1) * 1024;
  char* lU0 = (char*)Bu + (w * 2 + 0) * 1024;
  char* lU1 = (char*)Bu + (w * 2 + 1) * 1024;

  floatx4 accg[4][4] = {};   // [c][i]
  floatx4 accu[4][4] = {};

  for (int k0 = 0; k0 < D; k0 += BK) {
    gl_lds16(pA0, lA0); gl_lds16(pA1, lA1);
    gl_lds16(pG0, lG0); gl_lds16(pG1, lG1);
    gl_lds16(pU0, lU0); gl_lds16(pU1, lU1);
    pA0 += BK; pA1 += BK; pG0 += BK; pG1 += BK; pU0 += BK; pU1 += BK;
    __syncthreads();
    half8 af[4];
    #pragma unroll
    for (int i = 0; i < 4; ++i)
      af[i] = *(const half8*)&As[(wr * 64 + i * 16 + lrow) * BK + quad * 8];
    #pragma unroll
    for (int c = 0; c < 4; ++c) {
      half8 bgc = *(const half8*)&Bg[(wc * 64 + c * 16 + lrow) * BK + quad * 8];
      half8 buc = *(const half8*)&Bu[(wc * 64 + c * 16 + lrow) * BK + quad * 8];
      #pragma unroll
      for (int i = 0; i < 4; ++i) {
        accg[c][i] = __builtin_amdgcn_mfma_f32_16x16x32_f16(af[i], bgc, accg[c][i], 0, 0, 0);
        accu[c][i] = __builtin_amdgcn_mfma_f32_16x16x32_f16(af[i], buc, accu[c][i], 0, 0, 0);
      }
    }
    __syncthreads();
  }
  #pragma unroll
  for (int c = 0; c < 4; ++c) {
    int col = n0 + wc * 64 + c * 16 + lrow;
    #pragma unroll
    for (int i = 0; i < 4; ++i) {
      int rowb = row0 + wr * 64 + i * 16 + quad * 4;
      #pragma unroll
      for (int reg = 0; reg < 4; ++reg) {
        float g = accg[c][i][reg], u = accu[c][i][reg];
        Hid[(size_t)(rowb + reg) * M + col] = (_Float16)(g / (1.f + expf(-g)) * u);
      }
    }
  }
}

// ---------------- down grouped GEMM -> per-slot rows Yp ----------------
__global__ __launch_bounds__(256, 2) void k_down(
    const _Float16* __restrict__ Hid, const _Float16* __restrict__ wdT,
    _Float16* __restrict__ Yp,
    const int* __restrict__ base, const int* __restrict__ pc) {
  int lin = blockIdx.x;
  int e = lin & 7;
  int r = lin >> 3;
  int nt = r % NT_DN;
  int mt = r / NT_DN;
  if (mt * TM >= pc[e]) return;
  int row0 = base[e] + mt * TM;
  int d0 = nt * TN;
  __shared__ _Float16 As[TM * BK];
  __shared__ _Float16 Bs[TN * BK];
  int tid = threadIdx.x;
  int w = tid >> 6, lane = tid & 63;
  int lrow = lane & 15, quad = lane >> 4;
  int wr = w >> 1, wc = w & 1;
  int sr = lane >> 2, sc = (lane & 3) * 8;

  const _Float16* wd_e = wdT + (size_t)e * D * M;
  const _Float16* pA0 = Hid + (size_t)(row0 + w * 32 + sr) * M + sc;
  const _Float16* pA1 = Hid + (size_t)(row0 + w * 32 + 16 + sr) * M + sc;
  const _Float16* pB0 = wd_e + (size_t)(d0 + w * 32 + sr) * M + sc;
  const _Float16* pB1 = wd_e + (size_t)(d0 + w * 32 + 16 + sr) * M + sc;
  char* lA0 = (char*)As + (w * 2 + 0) * 1024;
  char* lA1 = (char*)As + (w * 2 + 1) * 1024;
  char* lB0 = (char*)Bs + (w * 2 + 0) * 1024;
  char* lB1 = (char*)Bs + (w * 2 + 1) * 1024;

  floatx4 acc[4][4] = {};

  for (int k0 = 0; k0 < M; k0 += BK) {
    gl_lds16(pA0, lA0); gl_lds16(pA1, lA1);
    gl_lds16(pB0, lB0); gl_lds16(pB1, lB1);
    pA0 += BK; pA1 += BK; pB0 += BK; pB1 += BK;
    __syncthreads();
    half8 af[4];
    #pragma unroll
    for (int i = 0; i < 4; ++i)
      af[i] = *(const half8*)&As[(wr * 64 + i * 16 + lrow) * BK + quad * 8];
    #pragma unroll
    for (int c = 0; c < 4; ++c) {
      half8 bc = *(const half8*)&Bs[(wc * 64 + c * 16 + lrow) * BK + quad * 8];
      #pragma unroll
      for (int i = 0; i < 4; ++i)
        acc[c][i] = __builtin_amdgcn_mfma_f32_16x16x32_f16(af[i], bc, acc[c][i], 0, 0, 0);
    }
    __syncthreads();
  }
  #pragma unroll
  for (int c = 0; c < 4; ++c) {
    int col = d0 + wc * 64 + c * 16 + lrow;
    #pragma unroll
    for (int i = 0; i < 4; ++i) {
      int rowb = row0 + wr * 64 + i * 16 + quad * 4;
      #pragma unroll
      for (int reg = 0; reg < 4; ++reg)
        Yp[(size_t)(rowb + reg) * D + col] = (_Float16)acc[c][i][reg];
    }
  }
}

// ---------------- combine: y[t] = p0*Yp[r0] + p1*Yp[r1] ----------------
__global__ __launch_bounds__(256) void k_combine(
    const _Float16* __restrict__ Yp, const int* __restrict__ base,
    const int* __restrict__ t2e, const int* __restrict__ t2pos,
    const float* __restrict__ t2p, float* __restrict__ out) {
  int t = blockIdx.x;
  int r0 = base[t2e[2 * t]]     + t2pos[2 * t];
  int r1 = base[t2e[2 * t + 1]] + t2pos[2 * t + 1];
  float p0 = t2p[2 * t], p1 = t2p[2 * t + 1];
  int d = threadIdx.x * 4;
  half4 h0 = *(const half4*)(Yp + (size_t)r0 * D + d);
  half4 h1 = *(const half4*)(Yp + (size_t)r1 * D + d);
  float4 o;
  o.x = p0 * (float)h0.x + p1 * (float)h1.x;
  o.y = p0 * (float)h0.y + p1 * (float)h1.y;
  o.z = p0 * (float)h0.z + p1 * (float)h1.z;
  o.w = p0 * (float)h0.w + p1 * (float)h1.w;
  *(float4*)(out + (size_t)t * D + d) = o;
}

// ---------------- launch ----------------
extern "C" void kernel_launch(void* const* d_in, const int* in_sizes, int n_in,
                              void* d_out, int out_size, void* d_ws, size_t ws_size,
                              hipStream_t stream) {
  const float* x     = (const float*)d_in[0];
  const float* wgate = (const float*)d_in[1];
  const float* w_g   = (const float*)d_in[2];
  const float* w_u   = (const float*)d_in[3];
  const float* w_d   = (const float*)d_in[4];
  float* out = (float*)d_out;
  char* ws = (char*)d_ws;

  if (ws_size < WS_NEED) {
    fprintf(stderr, "kernel_launch: ws_size=%zu < needed %zu\n", ws_size, WS_NEED);
    return;
  }

  int* counts = (int*)(ws + OFF_COUNTS);
  int* base   = (int*)(ws + OFF_BASE);
  int* pcn    = (int*)(ws + OFF_PC);
  int* total  = (int*)(ws + OFF_TOTAL);
  int* t2e    = (int*)(ws + OFF_T2E);
  int* t2pos  = (int*)(ws + OFF_T2POS);
  float* t2p  = (float*)(ws + OFF_T2P);
  int* tlist  = (int*)(ws + OFF_TLIST);
  _Float16* Xg  = (_Float16*)(ws + OFF_XG);   // later reused as Yp
  _Float16* Hid = (_Float16*)(ws + OFF_HID);
  _Float16* wgT = (_Float16*)(ws + OFF_WGT);
  _Float16* wuT = (_Float16*)(ws + OFF_WUT);
  _Float16* wdT = (_Float16*)(ws + OFF_WDT);

  hipMemsetAsync(ws, 0, OFF_T2E, stream);

  k_router<<<T / TOKB, 256, 0, stream>>>(x, wgate, counts, tlist, t2e, t2pos, t2p);
  k_scan<<<1, 64, 0, stream>>>(counts, base, pcn, total);
  k_gather<<<RCAP, 256, 0, stream>>>(x, counts, base, pcn, total, tlist, Xg);

  k_transpose<<<dim3(M / 32, D / 32, E), 256, 0, stream>>>(w_g, wgT, D, M);
  k_transpose<<<dim3(M / 32, D / 32, E), 256, 0, stream>>>(w_u, wuT, D, M);
  k_transpose<<<dim3(D / 32, M / 32, E), 256, 0, stream>>>(w_d, wdT, M, D);

  k_upgate<<<E * MT_MAX * NT_UP, 256, 0, stream>>>(Xg, wgT, wuT, Hid, base, pcn);
  _Float16* Yp = Xg;   // Xg dead; reuse as Yp
  k_down<<<E * MT_MAX * NT_DN, 256, 0, stream>>>(Hid, wdT, Yp, base, pcn);
  k_combine<<<T, 256, 0, stream>>>(Yp, base, t2e, t2pos, t2p, out);
}